// Round 1
// baseline (768.143 us; speedup 1.0000x reference)
//
#include <hip/hip_runtime.h>
#include <hip/hip_bf16.h>
#include <cstdint>
#include <cstddef>

#define N_ACT 200000
#define CH 128
#define NOFF 27
#define TM 128

typedef __bf16 v8bf __attribute__((ext_vector_type(8)));
typedef float v4f __attribute__((ext_vector_type(4)));

__device__ __forceinline__ unsigned short f2bf(float f) {
    union { float f; unsigned int u; } x; x.f = f;
    unsigned int lsb = (x.u >> 16) & 1u;
    x.u += 0x7fffu + lsb;            // round-to-nearest-even
    return (unsigned short)(x.u >> 16);
}

// K1a: cast features fp32 -> bf16, 8 elements/thread
__global__ void cast_feat(const float* __restrict__ in,
                          unsigned short* __restrict__ out) {
    long long i = (long long)blockIdx.x * blockDim.x + threadIdx.x;
    long long base = i * 8;
    if (base >= (long long)N_ACT * CH) return;
    const float4* p = (const float4*)(in + base);
    float4 a = p[0], b = p[1];
    unsigned int w0 = (unsigned)f2bf(a.x) | ((unsigned)f2bf(a.y) << 16);
    unsigned int w1 = (unsigned)f2bf(a.z) | ((unsigned)f2bf(a.w) << 16);
    unsigned int w2 = (unsigned)f2bf(b.x) | ((unsigned)f2bf(b.y) << 16);
    unsigned int w3 = (unsigned)f2bf(b.z) | ((unsigned)f2bf(b.w) << 16);
    *(uint4*)(out + base) = make_uint4(w0, w1, w2, w3);
}

// K1b: W[k][cin][cout] fp32 -> Wt[k][cout][cin] bf16; block 0 zeros stats
__global__ void prep_w(const float* __restrict__ W,
                       unsigned short* __restrict__ Wt,
                       float* __restrict__ stats) {
    int k = blockIdx.x;
    int t = threadIdx.x;
    if (k == 0 && t < 2 * CH) stats[t] = 0.0f;   // sums + sumsq
    const float* wk = W + (size_t)k * CH * CH;
    unsigned short* wo = Wt + (size_t)k * CH * CH;
    for (int g = t; g < CH * CH / 8; g += blockDim.x) {
        int co  = g >> 4;            // output channel (row of Wt)
        int ci0 = (g & 15) * 8;      // 8 consecutive input channels
        unsigned int wbuf[4];
        #pragma unroll
        for (int h = 0; h < 4; ++h) {
            unsigned short lo = f2bf(wk[(size_t)(ci0 + 2*h)     * CH + co]);
            unsigned short hi = f2bf(wk[(size_t)(ci0 + 2*h + 1) * CH + co]);
            wbuf[h] = (unsigned)lo | ((unsigned)hi << 16);
        }
        *(uint4*)(wo + (size_t)co * CH + ci0) =
            make_uint4(wbuf[0], wbuf[1], wbuf[2], wbuf[3]);
    }
}

// K2: gather + MFMA GEMM over 27 offsets; writes conv fp32 + column stats
__global__ __launch_bounds__(256, 2) void conv_mfma(
        const unsigned short* __restrict__ feat,   // [N][128] bf16
        const int* __restrict__ nbr,               // [27][N]
        const unsigned short* __restrict__ Wt,     // [27][cout][cin] bf16
        float* __restrict__ out,                   // [N][128] conv result
        float* __restrict__ stats) {               // sums[128], sumsq[128]
    __shared__ __bf16 As[TM][CH + 8];   // +8 bf16 pad -> 2-way bank alias (free)
    __shared__ __bf16 Bs[CH][CH + 8];
    __shared__ float sredS[CH][2];
    __shared__ float sredQ[CH][2];

    const int t    = threadIdx.x;
    const int row0 = blockIdx.x * TM;
    const int wid  = t >> 6;
    const int lane = t & 63;
    const int wr   = (wid >> 1) * 64;   // wave row offset in tile
    const int wc   = (wid & 1) * 64;    // wave col offset in tile
    const int lr   = lane & 15;
    const int quad = lane >> 4;

    v4f acc[4][4];
    #pragma unroll
    for (int i = 0; i < 4; ++i)
        #pragma unroll
        for (int j = 0; j < 4; ++j)
            acc[i][j] = (v4f){0.f, 0.f, 0.f, 0.f};

    const int sr = t >> 4;          // staging row within a 16-row pass
    const int sc = (t & 15) * 8;    // staging col (bf16 units), 16B chunks

    for (int k = 0; k < NOFF; ++k) {
        // ---- stage A: gathered neighbor rows (zeros if inactive/off-end)
        #pragma unroll
        for (int p = 0; p < 8; ++p) {
            int r  = p * 16 + sr;
            int gr = row0 + r;
            int idx = (gr < N_ACT) ? nbr[(size_t)k * N_ACT + gr] : -1;
            uint4 v = make_uint4(0u, 0u, 0u, 0u);
            if (idx >= 0)
                v = *(const uint4*)(feat + (size_t)idx * CH + sc);
            *(uint4*)(&As[r][sc]) = v;
        }
        // ---- stage B: Wt[k] straight copy
        const unsigned short* wk = Wt + (size_t)k * CH * CH;
        #pragma unroll
        for (int p = 0; p < 8; ++p) {
            int r = p * 16 + sr;
            uint4 v = *(const uint4*)(wk + (size_t)r * CH + sc);
            *(uint4*)(&Bs[r][sc]) = v;
        }
        __syncthreads();
        // ---- MFMA: 4 k-subtiles of 32, 4x4 16x16 tiles per wave
        #pragma unroll
        for (int kk = 0; kk < 4; ++kk) {
            v8bf a[4], b[4];
            #pragma unroll
            for (int i = 0; i < 4; ++i)
                a[i] = *(const v8bf*)(&As[wr + i * 16 + lr][kk * 32 + quad * 8]);
            #pragma unroll
            for (int j = 0; j < 4; ++j)
                b[j] = *(const v8bf*)(&Bs[wc + j * 16 + lr][kk * 32 + quad * 8]);
            #pragma unroll
            for (int i = 0; i < 4; ++i)
                #pragma unroll
                for (int j = 0; j < 4; ++j)
                    acc[i][j] = __builtin_amdgcn_mfma_f32_16x16x32_bf16(
                        a[i], b[j], acc[i][j], 0, 0, 0);
        }
        __syncthreads();
    }

    // ---- epilogue: store conv result + per-column partial stats
    float psum[4] = {0.f, 0.f, 0.f, 0.f};
    float psq[4]  = {0.f, 0.f, 0.f, 0.f};
    #pragma unroll
    for (int i = 0; i < 4; ++i) {
        #pragma unroll
        for (int r = 0; r < 4; ++r) {
            int grow = row0 + wr + i * 16 + quad * 4 + r;
            if (grow < N_ACT) {
                #pragma unroll
                for (int j = 0; j < 4; ++j) {
                    float v = acc[i][j][r];
                    out[(size_t)grow * CH + wc + j * 16 + lr] = v;
                    psum[j] += v;
                    psq[j]  += v * v;
                }
            }
        }
    }
    // reduce across quads (lanes sharing a column differ by bits 16/32)
    #pragma unroll
    for (int j = 0; j < 4; ++j) {
        psum[j] += __shfl_xor(psum[j], 16, 64);
        psq[j]  += __shfl_xor(psq[j], 16, 64);
        psum[j] += __shfl_xor(psum[j], 32, 64);
        psq[j]  += __shfl_xor(psq[j], 32, 64);
    }
    if (quad == 0) {
        #pragma unroll
        for (int j = 0; j < 4; ++j) {
            int c = wc + j * 16 + lr;
            sredS[c][wid >> 1] = psum[j];
            sredQ[c][wid >> 1] = psq[j];
        }
    }
    __syncthreads();
    if (t < CH) {
        atomicAdd(&stats[t],      sredS[t][0] + sredS[t][1]);
        atomicAdd(&stats[CH + t], sredQ[t][0] + sredQ[t][1]);
    }
}

// K3: per-channel scale/shift from batch stats
__global__ void finalize_stats(const float* __restrict__ gamma,
                               const float* __restrict__ beta,
                               float* __restrict__ stats) {
    int c = threadIdx.x;
    if (c < CH) {
        float inv_n = 1.0f / (float)N_ACT;
        float mean  = stats[c] * inv_n;
        float var   = stats[CH + c] * inv_n - mean * mean;
        float sc    = gamma[c] * rsqrtf(var + 1e-4f);
        stats[2 * CH + c] = sc;
        stats[3 * CH + c] = beta[c] - mean * sc;
    }
}

// K4: out = relu(conv * scale[c] + shift[c]), float4
__global__ void bn_relu(const float* __restrict__ conv,
                        const float* __restrict__ stats,
                        float* __restrict__ out) {
    long long i = (long long)blockIdx.x * blockDim.x + threadIdx.x;
    if (i >= (long long)N_ACT * CH / 4) return;
    int c4 = (int)(i & 31) * 4;
    float4 v  = ((const float4*)conv)[i];
    float4 sc = *(const float4*)(stats + 2 * CH + c4);
    float4 sh = *(const float4*)(stats + 3 * CH + c4);
    float4 o;
    o.x = fmaxf(v.x * sc.x + sh.x, 0.f);
    o.y = fmaxf(v.y * sc.y + sh.y, 0.f);
    o.z = fmaxf(v.z * sc.z + sh.z, 0.f);
    o.w = fmaxf(v.w * sc.w + sh.w, 0.f);
    ((float4*)out)[i] = o;
}

extern "C" void kernel_launch(void* const* d_in, const int* in_sizes, int n_in,
                              void* d_out, int out_size, void* d_ws, size_t ws_size,
                              hipStream_t stream) {
    const float* features = (const float*)d_in[0];
    const int*   nbr      = (const int*)d_in[1];
    const float* W        = (const float*)d_in[2];
    const float* gamma    = (const float*)d_in[3];
    const float* beta     = (const float*)d_in[4];
    float* outp = (float*)d_out;

    char* ws = (char*)d_ws;
    // layout: feat_bf16 (51,200,000 B) | Wt (884,736 B) | conv fp32
    // (102,400,000 B) | stats (512 floats)
    unsigned short* feat_bf = (unsigned short*)ws;
    unsigned short* Wt      = (unsigned short*)(ws + 51200000);
    float* conv             = (float*)(ws + 51200000 + 884736);
    float* stats            = (float*)(ws + 51200000 + 884736 + 102400000);

    // 25,600,000 elems / 8 per thread = 3,200,000 threads
    cast_feat<<<12500, 256, 0, stream>>>(features, feat_bf);
    prep_w<<<NOFF, 256, 0, stream>>>(W, Wt, stats);
    conv_mfma<<<(N_ACT + TM - 1) / TM, 256, 0, stream>>>(feat_bf, nbr, Wt,
                                                         conv, stats);
    finalize_stats<<<1, CH, 0, stream>>>(gamma, beta, stats);
    bn_relu<<<25000, 256, 0, stream>>>(conv, stats, outp);
}